// Round 16
// baseline (76.911 us; speedup 1.0000x reference)
//
#include <hip/hip_runtime.h>
#include <hip/hip_fp16.h>

// SimpleGNN 2-layer GCN, linear collapse:
//   out = N^2 x W12 + (N 1) c1^T + 1 b2^T,   N = D^-1/2 (A+I) D^-1/2
//   W12 = W1@W2 (64x10), c1 = b1@W2.
//
// 4-kernel pipeline; intermediates yd/zd stored FP16 as FULL 32B rows
// (halves: ch0-9, ch10 = dis resp. n1, ch11-15 = 0), fp32 accumulation:
//   k_part    : chunk-private LDS counting sort by bucket (dst>>8) -> packed
//               arena + scanT row. Block NCB additionally computes W12/c1.
//   k_sortproj: per 256-node bucket, 512 thr: wave-shfl scans, per-wave
//               LDS histograms, block-parallel coalesced segment copy,
//               scattered ssrc writeout -> rowbe/dis; then register-direct
//               projection -> yd (uint4 fp16 rows).
//   k_aggA    : 2 lanes/node, lane h gathers uint4 (8 halves = 32B/edge,
//               3.2M requests/pass): zd[ch<10] = dis^2*(self+nbrs);
//               zd[10] = dis*(dis-ch sum) = n1.
//   k_aggB    : same over zd; out = dis*(..) + n1*c1 + b2 (fp32 out).

#define NN 100000
#define NE 1600000
#define NPB 256            // nodes per bucket
#define NB 391             // ceil(NN/NPB); NB*NPB = 100096
#define CHUNK 4096         // edges per partition block
#define NCB 391            // ceil(NE/CHUNK)
#define MAXB 5120          // per-bucket edge cap (mean 4096, +16 sigma)

// Partition (+ fused small GEMM in the extra block NCB).
__global__ __launch_bounds__(256) void k_part(const int* __restrict__ src,
                                              const int* __restrict__ dst,
                                              const float* __restrict__ W1,
                                              const float* __restrict__ W2,
                                              const float* __restrict__ b1,
                                              int* __restrict__ packed,
                                              int* __restrict__ scanT,
                                              float* __restrict__ W12,
                                              float* __restrict__ c1) {
    __shared__ int hist[NB];
    __shared__ int sc[256];
    __shared__ int cur[NB];
    __shared__ int buf[CHUNK];
    int c = blockIdx.x, t = threadIdx.x;
    if (c == NCB) {   // fused k_small
        for (int o = t; o < 640; o += 256) {
            int k = o / 10, ch = o - k * 10;
            float acc = 0.f;
            #pragma unroll
            for (int m = 0; m < 64; ++m) acc = fmaf(W1[k * 64 + m], W2[m * 10 + ch], acc);
            W12[o] = acc;
        }
        if (t < 10) {
            float acc = 0.f;
            #pragma unroll
            for (int m = 0; m < 64; ++m) acc = fmaf(b1[m], W2[m * 10 + t], acc);
            c1[t] = acc;
        }
        return;
    }
    int e0 = c * CHUNK, e1 = min(e0 + CHUNK, NE);
    int n = e1 - e0;
    for (int i = t; i < NB; i += 256) hist[i] = 0;
    __syncthreads();
    int pk[16], bk[16];
    #pragma unroll
    for (int k = 0; k < 16; ++k) {
        int e = e0 + t + k * 256;
        if (e < e1) {
            int s = src[e], d = dst[e];
            pk[k] = (s << 8) | (d & 255);
            bk[k] = d >> 8;
            atomicAdd(&hist[bk[k]], 1);
        } else bk[k] = -1;
    }
    __syncthreads();
    // exclusive scan of hist[0..NB-1] via pair-compaction into 256-wide scan
    int i0 = 2 * t, i1 = 2 * t + 1;
    int h0 = (i0 < NB) ? hist[i0] : 0;
    int h1 = (i1 < NB) ? hist[i1] : 0;
    int ps = h0 + h1;
    sc[t] = ps; __syncthreads();
    for (int off = 1; off < 256; off <<= 1) {
        int a = (t >= off) ? sc[t - off] : 0;
        __syncthreads(); sc[t] += a; __syncthreads();
    }
    int exc = sc[t] - ps;
    if (i0 < NB) cur[i0] = exc;
    if (i1 < NB) cur[i1] = exc + h0;
    __syncthreads();
    for (int b = t; b < NB; b += 256) scanT[c * (NB + 1) + b] = e0 + cur[b];
    if (t == 0) scanT[c * (NB + 1) + NB] = e0 + n;
    __syncthreads();
    #pragma unroll
    for (int k = 0; k < 16; ++k) {
        if (bk[k] >= 0) {
            int pos = atomicAdd(&cur[bk[k]], 1);
            buf[pos] = pk[k];
        }
    }
    __syncthreads();
    for (int i = t; i < n; i += 256) packed[e0 + i] = buf[i];
}

// Per-bucket counting sort + register projection; 512 thr, wave-shfl scans.
__global__ __launch_bounds__(512) void k_sortproj(const int* __restrict__ packed,
                                                  const int* __restrict__ scanT,
                                                  const float* __restrict__ x,
                                                  const float* __restrict__ W12g,
                                                  int* __restrict__ ssrc,
                                                  int2* __restrict__ rowbe,
                                                  float* __restrict__ dis,
                                                  uint4* __restrict__ ydu) {
    __shared__ int stage[MAXB];      // concatenated segments
    __shared__ int sstart[NCB];      // segment start in packed
    __shared__ int segoff[NCB + 1];  // exclusive offsets in stage
    __shared__ int wtot[8];
    __shared__ int cnt8[8][NPB];     // per-wave histograms
    __shared__ int cur[NPB];
    __shared__ float disl[NPB];
    __shared__ float Wl[640];
    __shared__ int totsh;
    int b = blockIdx.x, t = threadIdx.x;
    int lane = t & 63, w = t >> 6;
    int wbase = b * MAXB;

    for (int i = t; i < 8 * NPB; i += 512) ((int*)cnt8)[i] = 0;

    // ---- segment lengths + wave-shfl inclusive scan over 512 ----
    int myl = 0;
    if (t < NCB) {
        int s0 = scanT[t * (NB + 1) + b];
        int s1 = scanT[t * (NB + 1) + b + 1];
        sstart[t] = s0;
        myl = s1 - s0;
    }
    int v = myl;
    #pragma unroll
    for (int off = 1; off < 64; off <<= 1) {
        int u = __shfl_up(v, off);
        if (lane >= off) v += u;
    }
    if (lane == 63) wtot[w] = v;
    __syncthreads();
    if (t == 0) {
        int s = 0;
        #pragma unroll
        for (int i = 0; i < 8; ++i) { int xx = wtot[i]; wtot[i] = s; s += xx; }
        totsh = s;
    }
    __syncthreads();
    if (t < NCB) segoff[t] = v + wtot[w] - myl;
    if (t == 0) segoff[NCB] = totsh;
    __syncthreads();
    int Tfull = totsh;
    int T = min(Tfull, MAXB);

    // ---- block-parallel coalesced copy + per-wave histograms ----
    for (int i = t; i < Tfull; i += 512) {
        int lo = 0, hi = NCB;                       // segoff[lo] <= i < segoff[hi]
        while (hi - lo > 1) {
            int mid = (lo + hi) >> 1;
            if (segoff[mid] <= i) lo = mid; else hi = mid;
        }
        int p = packed[sstart[lo] + (i - segoff[lo])];
        if (i < MAXB) stage[i] = p;
        atomicAdd(&cnt8[w][p & 255], 1);
    }
    __syncthreads();
    // ---- combine histograms + wave-shfl scan over 256 (waves 0-3) ----
    int hsum = 0, incl = 0;
    if (t < NPB) {
        #pragma unroll
        for (int i = 0; i < 8; ++i) hsum += cnt8[i][t];
        int vv = hsum;
        #pragma unroll
        for (int off = 1; off < 64; off <<= 1) {
            int u = __shfl_up(vv, off);
            if (lane >= off) vv += u;
        }
        if (lane == 63) wtot[w] = vv;
        incl = vv;
    }
    __syncthreads();
    if (t == 0) {
        int s = 0;
        #pragma unroll
        for (int i = 0; i < 4; ++i) { int xx = wtot[i]; wtot[i] = s; s += xx; }
    }
    __syncthreads();
    if (t < NPB) {
        int exc = incl + wtot[w] - hsum;
        int nidx = b * NPB + t;
        float dh = rsqrtf((float)hsum + 1.0f);
        disl[t] = dh;
        if (nidx < NN) {
            rowbe[nidx] = make_int2(wbase + min(exc, MAXB), wbase + min(exc + hsum, MAXB));
            dis[nidx] = dh;
        }
        cur[t] = wbase + exc;
    }
    for (int i = t; i < 640; i += 512) Wl[i] = W12g[i];
    __syncthreads();
    // ---- scatter to ssrc (dst-sorted within bucket window) ----
    {
        int wlim = wbase + MAXB;
        for (int i = t; i < T; i += 512) {
            int p = stage[i];
            int pos = atomicAdd(&cur[p & 255], 1);
            if (pos < wlim) ssrc[pos] = p >> 8;
        }
    }
    __syncthreads();

    // ---- phase 2: register-direct projection, thread-pair per row ----
    int r = t >> 1, h = t & 1;         // r in 0..255
    int n = b * NPB + r;
    if (n < NN) {
        const float* xr = &x[n * 64 + h * 32];
        float4 xa[8];
        #pragma unroll
        for (int i = 0; i < 8; ++i) xa[i] = *(const float4*)&xr[i * 4];
        float acc[10];
        #pragma unroll
        for (int ch = 0; ch < 10; ++ch) acc[ch] = 0.f;
        #pragma unroll
        for (int i = 0; i < 8; ++i) {
            int k0 = h * 32 + i * 4;
            #pragma unroll
            for (int ch = 0; ch < 10; ++ch) {
                acc[ch] = fmaf(xa[i].x, Wl[(k0 + 0) * 10 + ch], acc[ch]);
                acc[ch] = fmaf(xa[i].y, Wl[(k0 + 1) * 10 + ch], acc[ch]);
                acc[ch] = fmaf(xa[i].z, Wl[(k0 + 2) * 10 + ch], acc[ch]);
                acc[ch] = fmaf(xa[i].w, Wl[(k0 + 3) * 10 + ch], acc[ch]);
            }
        }
        #pragma unroll
        for (int ch = 0; ch < 10; ++ch) acc[ch] += __shfl_xor(acc[ch], 1);
        float dh = disl[r];
        uint4 wv;
        if (h == 0) {   // halves 0-7 = ch0-7
            __half2 p0 = __floats2half2_rn(dh * acc[0], dh * acc[1]);
            __half2 p1 = __floats2half2_rn(dh * acc[2], dh * acc[3]);
            __half2 p2 = __floats2half2_rn(dh * acc[4], dh * acc[5]);
            __half2 p3 = __floats2half2_rn(dh * acc[6], dh * acc[7]);
            wv.x = *(unsigned*)&p0; wv.y = *(unsigned*)&p1;
            wv.z = *(unsigned*)&p2; wv.w = *(unsigned*)&p3;
            ydu[n * 2 + 0] = wv;
        } else {        // halves 8-15 = ch8, ch9, dis, 0, 0,0,0,0
            __half2 p0 = __floats2half2_rn(dh * acc[8], dh * acc[9]);
            __half2 p1 = __floats2half2_rn(dh, 0.f);
            __half2 pz = __floats2half2_rn(0.f, 0.f);
            wv.x = *(unsigned*)&p0; wv.y = *(unsigned*)&p1;
            wv.z = *(unsigned*)&pz; wv.w = *(unsigned*)&pz;
            ydu[n * 2 + 1] = wv;
        }
    }
}

__device__ __forceinline__ void cvt8(uint4 v, float* f) {
    __half2 h0 = *(__half2*)&v.x, h1 = *(__half2*)&v.y;
    __half2 h2 = *(__half2*)&v.z, h3 = *(__half2*)&v.w;
    float2 a = __half22float2(h0), b = __half22float2(h1);
    float2 c = __half22float2(h2), d = __half22float2(h3);
    f[0] = a.x; f[1] = a.y; f[2] = b.x; f[3] = b.y;
    f[4] = c.x; f[5] = c.y; f[6] = d.x; f[7] = d.y;
}

// Pass 1: 2 lanes/node, lane h gathers uint4 (8 halves); 4-deep unroll.
// zd halves 0-7 = dis^2*s[0..7]; halves 8-15 = (dis^2*s8, dis^2*s9, dis*s10, 0...).
__global__ __launch_bounds__(256) void k_aggA(const uint4* __restrict__ ydu,
                                              const float* __restrict__ dis,
                                              const int2* __restrict__ rowbe,
                                              const int* __restrict__ ssrc,
                                              uint4* __restrict__ zdu) {
    int t = blockIdx.x * blockDim.x + threadIdx.x;
    int n = t >> 1, h = t & 1;
    if (n >= NN) return;
    int2 be = rowbe[n];
    float a0[8], a1[8], a2[8], a3[8];
    cvt8(ydu[n * 2 + h], a0);   // self term (dis folded in)
    #pragma unroll
    for (int i = 0; i < 8; ++i) { a1[i] = 0.f; a2[i] = 0.f; a3[i] = 0.f; }
    int j = be.x;
    for (; j + 3 < be.y; j += 4) {
        int s0 = ssrc[j], s1 = ssrc[j + 1], s2 = ssrc[j + 2], s3 = ssrc[j + 3];
        float v0[8], v1[8], v2[8], v3[8];
        cvt8(ydu[s0 * 2 + h], v0);
        cvt8(ydu[s1 * 2 + h], v1);
        cvt8(ydu[s2 * 2 + h], v2);
        cvt8(ydu[s3 * 2 + h], v3);
        #pragma unroll
        for (int i = 0; i < 8; ++i) {
            a0[i] += v0[i]; a1[i] += v1[i]; a2[i] += v2[i]; a3[i] += v3[i];
        }
    }
    for (; j < be.y; ++j) {
        float v[8];
        cvt8(ydu[ssrc[j] * 2 + h], v);
        #pragma unroll
        for (int i = 0; i < 8; ++i) a0[i] += v[i];
    }
    float s[8];
    #pragma unroll
    for (int i = 0; i < 8; ++i) s[i] = (a0[i] + a1[i]) + (a2[i] + a3[i]);
    float d = dis[n], d2 = d * d;
    uint4 wv;
    if (h == 0) {
        __half2 p0 = __floats2half2_rn(d2 * s[0], d2 * s[1]);
        __half2 p1 = __floats2half2_rn(d2 * s[2], d2 * s[3]);
        __half2 p2 = __floats2half2_rn(d2 * s[4], d2 * s[5]);
        __half2 p3 = __floats2half2_rn(d2 * s[6], d2 * s[7]);
        wv.x = *(unsigned*)&p0; wv.y = *(unsigned*)&p1;
        wv.z = *(unsigned*)&p2; wv.w = *(unsigned*)&p3;
    } else {
        __half2 p0 = __floats2half2_rn(d2 * s[0], d2 * s[1]);   // ch8, ch9
        __half2 p1 = __floats2half2_rn(d * s[2], 0.f);          // n1, 0
        __half2 pz = __floats2half2_rn(0.f, 0.f);
        wv.x = *(unsigned*)&p0; wv.y = *(unsigned*)&p1;
        wv.z = *(unsigned*)&pz; wv.w = *(unsigned*)&pz;
    }
    zdu[n * 2 + h] = wv;
}

// Pass 2: out[n][c] = dis*(zd self+nbrs)[c] + n1*c1[c] + b2[c].
__global__ __launch_bounds__(256) void k_aggB(const uint4* __restrict__ zdu,
                                              const float* __restrict__ dis,
                                              const int2* __restrict__ rowbe,
                                              const int* __restrict__ ssrc,
                                              const float* __restrict__ c1,
                                              const float* __restrict__ b2,
                                              float* __restrict__ out) {
    int t = blockIdx.x * blockDim.x + threadIdx.x;
    int n = t >> 1, h = t & 1;
    if (n >= NN) return;
    int2 be = rowbe[n];
    float a0[8], a1[8], a2[8], a3[8];
    cvt8(zdu[n * 2 + h], a0);   // self term
    float selfn1 = a0[2];       // lane h=1 holds zd[n][10] here
    #pragma unroll
    for (int i = 0; i < 8; ++i) { a1[i] = 0.f; a2[i] = 0.f; a3[i] = 0.f; }
    int j = be.x;
    for (; j + 3 < be.y; j += 4) {
        int s0 = ssrc[j], s1 = ssrc[j + 1], s2 = ssrc[j + 2], s3 = ssrc[j + 3];
        float v0[8], v1[8], v2[8], v3[8];
        cvt8(zdu[s0 * 2 + h], v0);
        cvt8(zdu[s1 * 2 + h], v1);
        cvt8(zdu[s2 * 2 + h], v2);
        cvt8(zdu[s3 * 2 + h], v3);
        #pragma unroll
        for (int i = 0; i < 8; ++i) {
            a0[i] += v0[i]; a1[i] += v1[i]; a2[i] += v2[i]; a3[i] += v3[i];
        }
    }
    for (; j < be.y; ++j) {
        float v[8];
        cvt8(zdu[ssrc[j] * 2 + h], v);
        #pragma unroll
        for (int i = 0; i < 8; ++i) a0[i] += v[i];
    }
    float s[8];
    #pragma unroll
    for (int i = 0; i < 8; ++i) s[i] = (a0[i] + a1[i]) + (a2[i] + a3[i]);
    float n1 = __shfl(selfn1, 1, 2);   // zd[n][10] from lane h=1's self load
    float d = dis[n];
    if (h == 0) {
        float2* o = (float2*)&out[n * 10];   // 8B aligned (40n % 8 == 0)
        o[0] = make_float2(fmaf(d, s[0], fmaf(n1, c1[0], b2[0])),
                           fmaf(d, s[1], fmaf(n1, c1[1], b2[1])));
        o[1] = make_float2(fmaf(d, s[2], fmaf(n1, c1[2], b2[2])),
                           fmaf(d, s[3], fmaf(n1, c1[3], b2[3])));
        o[2] = make_float2(fmaf(d, s[4], fmaf(n1, c1[4], b2[4])),
                           fmaf(d, s[5], fmaf(n1, c1[5], b2[5])));
        o[3] = make_float2(fmaf(d, s[6], fmaf(n1, c1[6], b2[6])),
                           fmaf(d, s[7], fmaf(n1, c1[7], b2[7])));
    } else {
        *(float2*)&out[n * 10 + 8] =
            make_float2(fmaf(d, s[0], fmaf(n1, c1[8], b2[8])),
                        fmaf(d, s[1], fmaf(n1, c1[9], b2[9])));
    }
}

extern "C" void kernel_launch(void* const* d_in, const int* in_sizes, int n_in,
                              void* d_out, int out_size, void* d_ws, size_t ws_size,
                              hipStream_t stream) {
    const float* x  = (const float*)d_in[0];
    const float* W1 = (const float*)d_in[1];
    const float* b1 = (const float*)d_in[2];
    const float* W2 = (const float*)d_in[3];
    const float* b2 = (const float*)d_in[4];
    const int* edge = (const int*)d_in[5];   // [2, NE]: src row then dst row
    const int* src = edge;
    const int* dst = edge + NE;
    float* out = (float*)d_out;

    // Workspace layout (64B-aligned), total ~22.6 MB:
    char* W = (char*)d_ws;
    uint4* ydu    = (uint4*)(W);                   // NN*2 uint4  = 3,200,000 B
    uint4* zdu    = (uint4*)(W + 3200000);         // NN*2 uint4  = 3,200,000 B
    float* dis    = (float*)(W + 6400000);         // NN f        =   400,000 B
    int*   packed = (int*)  (W + 6800000);         // NE i        = 6,400,000 B
    int*   scanT  = (int*)  (W + 13200000);        // NCB*(NB+1)  =   613,088 B
    int*   ssrc   = (int*)  (W + 13813120);        // NB*MAXB i   = 8,007,680 B
    int2*  rowbe  = (int2*) (W + 21820800);        // NN int2     =   800,000 B
    float* W12    = (float*)(W + 22620800);        // 640 f
    float* c1     = (float*)(W + 22623360);        // 10 f

    k_part    <<<NCB + 1, 256, 0, stream>>>(src, dst, W1, W2, b1, packed, scanT, W12, c1);
    k_sortproj<<<NB, 512, 0, stream>>>(packed, scanT, x, W12, ssrc, rowbe, dis, ydu);
    k_aggA    <<<(NN * 2 + 255) / 256, 256, 0, stream>>>(ydu, dis, rowbe, ssrc, zdu);
    k_aggB    <<<(NN * 2 + 255) / 256, 256, 0, stream>>>(zdu, dis, rowbe, ssrc, c1, b2, out);
}

// Round 17
// 75.223 us; speedup vs baseline: 1.0224x; 1.0224x over previous
//
#include <hip/hip_runtime.h>
#include <hip/hip_fp16.h>

// SimpleGNN 2-layer GCN, linear collapse:
//   out = N^2 x W12 + (N 1) c1^T + 1 b2^T,   N = D^-1/2 (A+I) D^-1/2
//   W12 = W1@W2 (64x10), c1 = b1@W2.
//
// 4-kernel pipeline; intermediates yd/zd stored FP16 as FULL 32B rows
// (halves: ch0-9, ch10 = dis resp. n1, ch11-15 = 0), fp32 accumulation:
//   k_part    : chunk-private LDS counting sort by bucket (dst>>8) -> packed
//               arena + scanT row. Block NCB additionally computes W12/c1.
//   k_sortproj: per 256-node bucket, 512 thr: wave-shfl scans, per-wave
//               LDS histograms, block-parallel coalesced segment copy,
//               scattered ssrc writeout -> rowbe/dis; then register-direct
//               projection -> yd (uint4 fp16 rows).
//   k_aggA    : 4 lanes/node, lane q<3 gathers uint2 (4 halves = 24B/edge,
//               400K threads): zd[ch<10] = dis^2*(self+nbrs); zd[10] = n1.
//   k_aggB    : same over zd; out = dis*(..) + n1*c1 + b2 (fp32 out).

#define NN 100000
#define NE 1600000
#define NPB 256            // nodes per bucket
#define NB 391             // ceil(NN/NPB); NB*NPB = 100096
#define CHUNK 4096         // edges per partition block
#define NCB 391            // ceil(NE/CHUNK)
#define MAXB 5120          // per-bucket edge cap (mean 4096, +16 sigma)

// Partition (+ fused small GEMM in the extra block NCB).
__global__ __launch_bounds__(256) void k_part(const int* __restrict__ src,
                                              const int* __restrict__ dst,
                                              const float* __restrict__ W1,
                                              const float* __restrict__ W2,
                                              const float* __restrict__ b1,
                                              int* __restrict__ packed,
                                              int* __restrict__ scanT,
                                              float* __restrict__ W12,
                                              float* __restrict__ c1) {
    __shared__ int hist[NB];
    __shared__ int sc[256];
    __shared__ int cur[NB];
    __shared__ int buf[CHUNK];
    int c = blockIdx.x, t = threadIdx.x;
    if (c == NCB) {   // fused k_small
        for (int o = t; o < 640; o += 256) {
            int k = o / 10, ch = o - k * 10;
            float acc = 0.f;
            #pragma unroll
            for (int m = 0; m < 64; ++m) acc = fmaf(W1[k * 64 + m], W2[m * 10 + ch], acc);
            W12[o] = acc;
        }
        if (t < 10) {
            float acc = 0.f;
            #pragma unroll
            for (int m = 0; m < 64; ++m) acc = fmaf(b1[m], W2[m * 10 + t], acc);
            c1[t] = acc;
        }
        return;
    }
    int e0 = c * CHUNK, e1 = min(e0 + CHUNK, NE);
    int n = e1 - e0;
    for (int i = t; i < NB; i += 256) hist[i] = 0;
    __syncthreads();
    int pk[16], bk[16];
    #pragma unroll
    for (int k = 0; k < 16; ++k) {
        int e = e0 + t + k * 256;
        if (e < e1) {
            int s = src[e], d = dst[e];
            pk[k] = (s << 8) | (d & 255);
            bk[k] = d >> 8;
            atomicAdd(&hist[bk[k]], 1);
        } else bk[k] = -1;
    }
    __syncthreads();
    // exclusive scan of hist[0..NB-1] via pair-compaction into 256-wide scan
    int i0 = 2 * t, i1 = 2 * t + 1;
    int h0 = (i0 < NB) ? hist[i0] : 0;
    int h1 = (i1 < NB) ? hist[i1] : 0;
    int ps = h0 + h1;
    sc[t] = ps; __syncthreads();
    for (int off = 1; off < 256; off <<= 1) {
        int a = (t >= off) ? sc[t - off] : 0;
        __syncthreads(); sc[t] += a; __syncthreads();
    }
    int exc = sc[t] - ps;
    if (i0 < NB) cur[i0] = exc;
    if (i1 < NB) cur[i1] = exc + h0;
    __syncthreads();
    for (int b = t; b < NB; b += 256) scanT[c * (NB + 1) + b] = e0 + cur[b];
    if (t == 0) scanT[c * (NB + 1) + NB] = e0 + n;
    __syncthreads();
    #pragma unroll
    for (int k = 0; k < 16; ++k) {
        if (bk[k] >= 0) {
            int pos = atomicAdd(&cur[bk[k]], 1);
            buf[pos] = pk[k];
        }
    }
    __syncthreads();
    for (int i = t; i < n; i += 256) packed[e0 + i] = buf[i];
}

// Per-bucket counting sort + register projection; 512 thr, wave-shfl scans.
__global__ __launch_bounds__(512) void k_sortproj(const int* __restrict__ packed,
                                                  const int* __restrict__ scanT,
                                                  const float* __restrict__ x,
                                                  const float* __restrict__ W12g,
                                                  int* __restrict__ ssrc,
                                                  int2* __restrict__ rowbe,
                                                  float* __restrict__ dis,
                                                  uint4* __restrict__ ydu) {
    __shared__ int stage[MAXB];      // concatenated segments
    __shared__ int sstart[NCB];      // segment start in packed
    __shared__ int segoff[NCB + 1];  // exclusive offsets in stage
    __shared__ int wtot[8];
    __shared__ int cnt8[8][NPB];     // per-wave histograms
    __shared__ int cur[NPB];
    __shared__ float disl[NPB];
    __shared__ float Wl[640];
    __shared__ int totsh;
    int b = blockIdx.x, t = threadIdx.x;
    int lane = t & 63, w = t >> 6;
    int wbase = b * MAXB;

    for (int i = t; i < 8 * NPB; i += 512) ((int*)cnt8)[i] = 0;

    // ---- segment lengths + wave-shfl inclusive scan over 512 ----
    int myl = 0;
    if (t < NCB) {
        int s0 = scanT[t * (NB + 1) + b];
        int s1 = scanT[t * (NB + 1) + b + 1];
        sstart[t] = s0;
        myl = s1 - s0;
    }
    int v = myl;
    #pragma unroll
    for (int off = 1; off < 64; off <<= 1) {
        int u = __shfl_up(v, off);
        if (lane >= off) v += u;
    }
    if (lane == 63) wtot[w] = v;
    __syncthreads();
    if (t == 0) {
        int s = 0;
        #pragma unroll
        for (int i = 0; i < 8; ++i) { int xx = wtot[i]; wtot[i] = s; s += xx; }
        totsh = s;
    }
    __syncthreads();
    if (t < NCB) segoff[t] = v + wtot[w] - myl;
    if (t == 0) segoff[NCB] = totsh;
    __syncthreads();
    int Tfull = totsh;
    int T = min(Tfull, MAXB);

    // ---- block-parallel coalesced copy + per-wave histograms ----
    for (int i = t; i < Tfull; i += 512) {
        int lo = 0, hi = NCB;                       // segoff[lo] <= i < segoff[hi]
        while (hi - lo > 1) {
            int mid = (lo + hi) >> 1;
            if (segoff[mid] <= i) lo = mid; else hi = mid;
        }
        int p = packed[sstart[lo] + (i - segoff[lo])];
        if (i < MAXB) stage[i] = p;
        atomicAdd(&cnt8[w][p & 255], 1);
    }
    __syncthreads();
    // ---- combine histograms + wave-shfl scan over 256 (waves 0-3) ----
    int hsum = 0, incl = 0;
    if (t < NPB) {
        #pragma unroll
        for (int i = 0; i < 8; ++i) hsum += cnt8[i][t];
        int vv = hsum;
        #pragma unroll
        for (int off = 1; off < 64; off <<= 1) {
            int u = __shfl_up(vv, off);
            if (lane >= off) vv += u;
        }
        if (lane == 63) wtot[w] = vv;
        incl = vv;
    }
    __syncthreads();
    if (t == 0) {
        int s = 0;
        #pragma unroll
        for (int i = 0; i < 4; ++i) { int xx = wtot[i]; wtot[i] = s; s += xx; }
    }
    __syncthreads();
    if (t < NPB) {
        int exc = incl + wtot[w] - hsum;
        int nidx = b * NPB + t;
        float dh = rsqrtf((float)hsum + 1.0f);
        disl[t] = dh;
        if (nidx < NN) {
            rowbe[nidx] = make_int2(wbase + min(exc, MAXB), wbase + min(exc + hsum, MAXB));
            dis[nidx] = dh;
        }
        cur[t] = wbase + exc;
    }
    for (int i = t; i < 640; i += 512) Wl[i] = W12g[i];
    __syncthreads();
    // ---- scatter to ssrc (dst-sorted within bucket window) ----
    {
        int wlim = wbase + MAXB;
        for (int i = t; i < T; i += 512) {
            int p = stage[i];
            int pos = atomicAdd(&cur[p & 255], 1);
            if (pos < wlim) ssrc[pos] = p >> 8;
        }
    }
    __syncthreads();

    // ---- phase 2: register-direct projection, thread-pair per row ----
    int r = t >> 1, h = t & 1;         // r in 0..255
    int n = b * NPB + r;
    if (n < NN) {
        const float* xr = &x[n * 64 + h * 32];
        float4 xa[8];
        #pragma unroll
        for (int i = 0; i < 8; ++i) xa[i] = *(const float4*)&xr[i * 4];
        float acc[10];
        #pragma unroll
        for (int ch = 0; ch < 10; ++ch) acc[ch] = 0.f;
        #pragma unroll
        for (int i = 0; i < 8; ++i) {
            int k0 = h * 32 + i * 4;
            #pragma unroll
            for (int ch = 0; ch < 10; ++ch) {
                acc[ch] = fmaf(xa[i].x, Wl[(k0 + 0) * 10 + ch], acc[ch]);
                acc[ch] = fmaf(xa[i].y, Wl[(k0 + 1) * 10 + ch], acc[ch]);
                acc[ch] = fmaf(xa[i].z, Wl[(k0 + 2) * 10 + ch], acc[ch]);
                acc[ch] = fmaf(xa[i].w, Wl[(k0 + 3) * 10 + ch], acc[ch]);
            }
        }
        #pragma unroll
        for (int ch = 0; ch < 10; ++ch) acc[ch] += __shfl_xor(acc[ch], 1);
        float dh = disl[r];
        uint4 wv;
        if (h == 0) {   // halves 0-7 = ch0-7
            __half2 p0 = __floats2half2_rn(dh * acc[0], dh * acc[1]);
            __half2 p1 = __floats2half2_rn(dh * acc[2], dh * acc[3]);
            __half2 p2 = __floats2half2_rn(dh * acc[4], dh * acc[5]);
            __half2 p3 = __floats2half2_rn(dh * acc[6], dh * acc[7]);
            wv.x = *(unsigned*)&p0; wv.y = *(unsigned*)&p1;
            wv.z = *(unsigned*)&p2; wv.w = *(unsigned*)&p3;
            ydu[n * 2 + 0] = wv;
        } else {        // halves 8-15 = ch8, ch9, dis, 0, 0,0,0,0
            __half2 p0 = __floats2half2_rn(dh * acc[8], dh * acc[9]);
            __half2 p1 = __floats2half2_rn(dh, 0.f);
            __half2 pz = __floats2half2_rn(0.f, 0.f);
            wv.x = *(unsigned*)&p0; wv.y = *(unsigned*)&p1;
            wv.z = *(unsigned*)&pz; wv.w = *(unsigned*)&pz;
            ydu[n * 2 + 1] = wv;
        }
    }
}

__device__ __forceinline__ float4 cvt4(uint2 v) {
    __half2 h0 = *(__half2*)&v.x, h1 = *(__half2*)&v.y;
    float2 f0 = __half22float2(h0), f1 = __half22float2(h1);
    return make_float4(f0.x, f0.y, f1.x, f1.y);
}

// Pass 1: 4 lanes/node, lane q<3 gathers uint2 (4 halves); 4-deep unroll.
// zd[ch<10] = dis^2*(self+nbrs); zd[10] = dis*(dis-ch sum); zd[11] = 0.
__global__ __launch_bounds__(256) void k_aggA(const uint2* __restrict__ ydu,
                                              const float* __restrict__ dis,
                                              const int2* __restrict__ rowbe,
                                              const int* __restrict__ ssrc,
                                              uint2* __restrict__ zdu) {
    int t = blockIdx.x * blockDim.x + threadIdx.x;
    int n = t >> 2, q = t & 3;
    if (n >= NN) return;
    int2 be = rowbe[n];
    const bool act = (q < 3);
    float4 a0 = make_float4(0.f, 0.f, 0.f, 0.f), a1 = a0, a2 = a0, a3 = a0;
    if (act) a0 = cvt4(ydu[n * 4 + q]);   // self term (dis folded in)
    int j = be.x;
    for (; j + 3 < be.y; j += 4) {
        int s0 = ssrc[j], s1 = ssrc[j + 1], s2 = ssrc[j + 2], s3 = ssrc[j + 3];
        if (act) {
            float4 v0 = cvt4(ydu[s0 * 4 + q]);
            float4 v1 = cvt4(ydu[s1 * 4 + q]);
            float4 v2 = cvt4(ydu[s2 * 4 + q]);
            float4 v3 = cvt4(ydu[s3 * 4 + q]);
            a0.x += v0.x; a0.y += v0.y; a0.z += v0.z; a0.w += v0.w;
            a1.x += v1.x; a1.y += v1.y; a1.z += v1.z; a1.w += v1.w;
            a2.x += v2.x; a2.y += v2.y; a2.z += v2.z; a2.w += v2.w;
            a3.x += v3.x; a3.y += v3.y; a3.z += v3.z; a3.w += v3.w;
        }
    }
    for (; j < be.y; ++j) {
        int s = ssrc[j];
        if (act) {
            float4 v = cvt4(ydu[s * 4 + q]);
            a0.x += v.x; a0.y += v.y; a0.z += v.z; a0.w += v.w;
        }
    }
    if (act) {
        float4 s;
        s.x = (a0.x + a1.x) + (a2.x + a3.x);
        s.y = (a0.y + a1.y) + (a2.y + a3.y);
        s.z = (a0.z + a1.z) + (a2.z + a3.z);
        s.w = (a0.w + a1.w) + (a2.w + a3.w);
        float d = dis[n], d2 = d * d;
        __half2 lo, hi;
        if (q < 2) {
            lo = __floats2half2_rn(d2 * s.x, d2 * s.y);
            hi = __floats2half2_rn(d2 * s.z, d2 * s.w);
        } else {
            lo = __floats2half2_rn(d2 * s.x, d2 * s.y);
            hi = __floats2half2_rn(d * s.z, 0.f);    // n1 = dis * (dis-ch sum)
        }
        uint2 w; w.x = *(unsigned*)&lo; w.y = *(unsigned*)&hi;
        zdu[n * 4 + q] = w;
    }
}

// Pass 2: out[n][c] = dis*(zd self+nbrs)[c] + n1*c1[c] + b2[c].
__global__ __launch_bounds__(256) void k_aggB(const uint2* __restrict__ zdu,
                                              const float* __restrict__ dis,
                                              const int2* __restrict__ rowbe,
                                              const int* __restrict__ ssrc,
                                              const float* __restrict__ c1,
                                              const float* __restrict__ b2,
                                              float* __restrict__ out) {
    int t = blockIdx.x * blockDim.x + threadIdx.x;
    int n = t >> 2, q = t & 3;
    if (n >= NN) return;
    int2 be = rowbe[n];
    const bool act = (q < 3);
    float4 self = make_float4(0.f, 0.f, 0.f, 0.f);
    if (act) self = cvt4(zdu[n * 4 + q]);
    float4 a0 = self, a1 = make_float4(0.f, 0.f, 0.f, 0.f), a2 = a1, a3 = a1;
    int j = be.x;
    for (; j + 3 < be.y; j += 4) {
        int s0 = ssrc[j], s1 = ssrc[j + 1], s2 = ssrc[j + 2], s3 = ssrc[j + 3];
        if (act) {
            float4 v0 = cvt4(zdu[s0 * 4 + q]);
            float4 v1 = cvt4(zdu[s1 * 4 + q]);
            float4 v2 = cvt4(zdu[s2 * 4 + q]);
            float4 v3 = cvt4(zdu[s3 * 4 + q]);
            a0.x += v0.x; a0.y += v0.y; a0.z += v0.z; a0.w += v0.w;
            a1.x += v1.x; a1.y += v1.y; a1.z += v1.z; a1.w += v1.w;
            a2.x += v2.x; a2.y += v2.y; a2.z += v2.z; a2.w += v2.w;
            a3.x += v3.x; a3.y += v3.y; a3.z += v3.z; a3.w += v3.w;
        }
    }
    for (; j < be.y; ++j) {
        int s = ssrc[j];
        if (act) {
            float4 v = cvt4(zdu[s * 4 + q]);
            a0.x += v.x; a0.y += v.y; a0.z += v.z; a0.w += v.w;
        }
    }
    float4 s;
    s.x = (a0.x + a1.x) + (a2.x + a3.x);
    s.y = (a0.y + a1.y) + (a2.y + a3.y);
    s.z = (a0.z + a1.z) + (a2.z + a3.z);
    s.w = (a0.w + a1.w) + (a2.w + a3.w);
    float n1 = __shfl(self.z, 2, 4);   // zd[n][10] from q2's self load
    float d = dis[n];
    if (q == 0) {
        out[n * 10 + 0] = fmaf(d, s.x, fmaf(n1, c1[0], b2[0]));
        out[n * 10 + 1] = fmaf(d, s.y, fmaf(n1, c1[1], b2[1]));
        out[n * 10 + 2] = fmaf(d, s.z, fmaf(n1, c1[2], b2[2]));
        out[n * 10 + 3] = fmaf(d, s.w, fmaf(n1, c1[3], b2[3]));
    } else if (q == 1) {
        out[n * 10 + 4] = fmaf(d, s.x, fmaf(n1, c1[4], b2[4]));
        out[n * 10 + 5] = fmaf(d, s.y, fmaf(n1, c1[5], b2[5]));
        out[n * 10 + 6] = fmaf(d, s.z, fmaf(n1, c1[6], b2[6]));
        out[n * 10 + 7] = fmaf(d, s.w, fmaf(n1, c1[7], b2[7]));
    } else if (q == 2) {
        out[n * 10 + 8] = fmaf(d, s.x, fmaf(n1, c1[8], b2[8]));
        out[n * 10 + 9] = fmaf(d, s.y, fmaf(n1, c1[9], b2[9]));
    }
}

extern "C" void kernel_launch(void* const* d_in, const int* in_sizes, int n_in,
                              void* d_out, int out_size, void* d_ws, size_t ws_size,
                              hipStream_t stream) {
    const float* x  = (const float*)d_in[0];
    const float* W1 = (const float*)d_in[1];
    const float* b1 = (const float*)d_in[2];
    const float* W2 = (const float*)d_in[3];
    const float* b2 = (const float*)d_in[4];
    const int* edge = (const int*)d_in[5];   // [2, NE]: src row then dst row
    const int* src = edge;
    const int* dst = edge + NE;
    float* out = (float*)d_out;

    // Workspace layout (64B-aligned), total ~22.6 MB:
    char* W = (char*)d_ws;
    uint4* ydu    = (uint4*)(W);                   // NN*2 uint4  = 3,200,000 B
    uint4* zdu    = (uint4*)(W + 3200000);         // NN*2 uint4  = 3,200,000 B
    float* dis    = (float*)(W + 6400000);         // NN f        =   400,000 B
    int*   packed = (int*)  (W + 6800000);         // NE i        = 6,400,000 B
    int*   scanT  = (int*)  (W + 13200000);        // NCB*(NB+1)  =   613,088 B
    int*   ssrc   = (int*)  (W + 13813120);        // NB*MAXB i   = 8,007,680 B
    int2*  rowbe  = (int2*) (W + 21820800);        // NN int2     =   800,000 B
    float* W12    = (float*)(W + 22620800);        // 640 f
    float* c1     = (float*)(W + 22623360);        // 10 f

    k_part    <<<NCB + 1, 256, 0, stream>>>(src, dst, W1, W2, b1, packed, scanT, W12, c1);
    k_sortproj<<<NB, 512, 0, stream>>>(packed, scanT, x, W12, ssrc, rowbe, dis, ydu);
    k_aggA    <<<(NN * 4 + 255) / 256, 256, 0, stream>>>((const uint2*)ydu, dis, rowbe, ssrc, (uint2*)zdu);
    k_aggB    <<<(NN * 4 + 255) / 256, 256, 0, stream>>>((const uint2*)zdu, dis, rowbe, ssrc, c1, b2, out);
}

// Round 18
// 70.836 us; speedup vs baseline: 1.0858x; 1.0619x over previous
//
#include <hip/hip_runtime.h>
#include <hip/hip_fp16.h>

// SimpleGNN 2-layer GCN, linear collapse:
//   out = N^2 x W12 + (N 1) c1^T + 1 b2^T,   N = D^-1/2 (A+I) D^-1/2
//   W12 = W1@W2 (64x10), c1 = b1@W2.
//
// 4-kernel pipeline; intermediates yd/zd stored FP16 as 32B rows
// (halves: ch0-9, ch10 = dis resp. n1, rest 0), fp32 accumulation:
//   k_part    : chunk-private LDS counting sort by bucket (dst>>8) -> packed
//               arena + scanT row. Block NCB additionally computes W12/c1.
//   k_sortproj: per 256-node bucket, 512 thr: wave-shfl scans + per-wave LDS
//               histograms + block-parallel coalesced segment copy ->
//               LDS reorder (dst-sorted) -> COALESCED ssrc writeout ->
//               rowbe/dis; then register-direct projection -> yd (fp16).
//   k_aggA    : 4 lanes/node, lane q<3 gathers uint2 (24B/edge, 400K thr):
//               zd[ch<10] = dis^2*(self+nbrs); zd[10] = dis*(dis-ch sum) = n1.
//   k_aggB    : same over zd; out = dis*(..) + n1*c1 + b2 (fp32 out).

#define NN 100000
#define NE 1600000
#define NPB 256            // nodes per bucket
#define NB 391             // ceil(NN/NPB); NB*NPB = 100096
#define CHUNK 4096         // edges per partition block
#define NCB 391            // ceil(NE/CHUNK)
#define MAXB 5120          // per-bucket edge cap (mean 4096, +16 sigma)

// Partition (+ fused small GEMM in the extra block NCB).
__global__ __launch_bounds__(256) void k_part(const int* __restrict__ src,
                                              const int* __restrict__ dst,
                                              const float* __restrict__ W1,
                                              const float* __restrict__ W2,
                                              const float* __restrict__ b1,
                                              int* __restrict__ packed,
                                              int* __restrict__ scanT,
                                              float* __restrict__ W12,
                                              float* __restrict__ c1) {
    __shared__ int hist[NB];
    __shared__ int sc[256];
    __shared__ int cur[NB];
    __shared__ int buf[CHUNK];
    int c = blockIdx.x, t = threadIdx.x;
    if (c == NCB) {   // fused k_small
        for (int o = t; o < 640; o += 256) {
            int k = o / 10, ch = o - k * 10;
            float acc = 0.f;
            #pragma unroll
            for (int m = 0; m < 64; ++m) acc = fmaf(W1[k * 64 + m], W2[m * 10 + ch], acc);
            W12[o] = acc;
        }
        if (t < 10) {
            float acc = 0.f;
            #pragma unroll
            for (int m = 0; m < 64; ++m) acc = fmaf(b1[m], W2[m * 10 + t], acc);
            c1[t] = acc;
        }
        return;
    }
    int e0 = c * CHUNK, e1 = min(e0 + CHUNK, NE);
    int n = e1 - e0;
    for (int i = t; i < NB; i += 256) hist[i] = 0;
    __syncthreads();
    int pk[16], bk[16];
    #pragma unroll
    for (int k = 0; k < 16; ++k) {
        int e = e0 + t + k * 256;
        if (e < e1) {
            int s = src[e], d = dst[e];
            pk[k] = (s << 8) | (d & 255);
            bk[k] = d >> 8;
            atomicAdd(&hist[bk[k]], 1);
        } else bk[k] = -1;
    }
    __syncthreads();
    // exclusive scan of hist[0..NB-1] via pair-compaction into 256-wide scan
    int i0 = 2 * t, i1 = 2 * t + 1;
    int h0 = (i0 < NB) ? hist[i0] : 0;
    int h1 = (i1 < NB) ? hist[i1] : 0;
    int ps = h0 + h1;
    sc[t] = ps; __syncthreads();
    for (int off = 1; off < 256; off <<= 1) {
        int a = (t >= off) ? sc[t - off] : 0;
        __syncthreads(); sc[t] += a; __syncthreads();
    }
    int exc = sc[t] - ps;
    if (i0 < NB) cur[i0] = exc;
    if (i1 < NB) cur[i1] = exc + h0;
    __syncthreads();
    for (int b = t; b < NB; b += 256) scanT[c * (NB + 1) + b] = e0 + cur[b];
    if (t == 0) scanT[c * (NB + 1) + NB] = e0 + n;
    __syncthreads();
    #pragma unroll
    for (int k = 0; k < 16; ++k) {
        if (bk[k] >= 0) {
            int pos = atomicAdd(&cur[bk[k]], 1);
            buf[pos] = pk[k];
        }
    }
    __syncthreads();
    for (int i = t; i < n; i += 256) packed[e0 + i] = buf[i];
}

// Per-bucket counting sort + register projection; 512 thr.
// Wave-shfl scans, per-wave histograms, LDS reorder + coalesced ssrc write.
__global__ __launch_bounds__(512) void k_sortproj(const int* __restrict__ packed,
                                                  const int* __restrict__ scanT,
                                                  const float* __restrict__ x,
                                                  const float* __restrict__ W12g,
                                                  int* __restrict__ ssrc,
                                                  int2* __restrict__ rowbe,
                                                  float* __restrict__ dis,
                                                  uint4* __restrict__ ydu) {
    __shared__ int stage[MAXB];      // concatenated segments
    __shared__ int sorted[MAXB];     // dst-sorted (relative positions)
    __shared__ int sstart[NCB];      // segment start in packed
    __shared__ int segoff[NCB + 1];  // exclusive offsets in stage
    __shared__ int wtot[8];
    __shared__ int cnt8[8][NPB];     // per-wave histograms
    __shared__ int cur[NPB];
    __shared__ float disl[NPB];
    __shared__ float Wl[640];
    __shared__ int totsh;
    int b = blockIdx.x, t = threadIdx.x;
    int lane = t & 63, w = t >> 6;
    int wbase = b * MAXB;

    for (int i = t; i < 8 * NPB; i += 512) ((int*)cnt8)[i] = 0;

    // ---- segment lengths + wave-shfl inclusive scan over 512 ----
    int myl = 0;
    if (t < NCB) {
        int s0 = scanT[t * (NB + 1) + b];
        int s1 = scanT[t * (NB + 1) + b + 1];
        sstart[t] = s0;
        myl = s1 - s0;
    }
    int v = myl;
    #pragma unroll
    for (int off = 1; off < 64; off <<= 1) {
        int u = __shfl_up(v, off);
        if (lane >= off) v += u;
    }
    if (lane == 63) wtot[w] = v;
    __syncthreads();
    if (t == 0) {
        int s = 0;
        #pragma unroll
        for (int i = 0; i < 8; ++i) { int xx = wtot[i]; wtot[i] = s; s += xx; }
        totsh = s;
    }
    __syncthreads();
    if (t < NCB) segoff[t] = v + wtot[w] - myl;
    if (t == 0) segoff[NCB] = totsh;
    __syncthreads();
    int Tfull = totsh;
    int T = min(Tfull, MAXB);

    // ---- block-parallel coalesced copy + per-wave histograms ----
    for (int i = t; i < Tfull; i += 512) {
        int lo = 0, hi = NCB;                       // segoff[lo] <= i < segoff[hi]
        while (hi - lo > 1) {
            int mid = (lo + hi) >> 1;
            if (segoff[mid] <= i) lo = mid; else hi = mid;
        }
        int p = packed[sstart[lo] + (i - segoff[lo])];
        if (i < MAXB) stage[i] = p;
        atomicAdd(&cnt8[w][p & 255], 1);
    }
    __syncthreads();
    // ---- combine histograms + wave-shfl scan over 256 (waves 0-3) ----
    int hsum = 0, incl = 0;
    if (t < NPB) {
        #pragma unroll
        for (int i = 0; i < 8; ++i) hsum += cnt8[i][t];
        int vv = hsum;
        #pragma unroll
        for (int off = 1; off < 64; off <<= 1) {
            int u = __shfl_up(vv, off);
            if (lane >= off) vv += u;
        }
        if (lane == 63) wtot[w] = vv;
        incl = vv;
    }
    __syncthreads();
    if (t == 0) {
        int s = 0;
        #pragma unroll
        for (int i = 0; i < 4; ++i) { int xx = wtot[i]; wtot[i] = s; s += xx; }
    }
    __syncthreads();
    if (t < NPB) {
        int exc = incl + wtot[w] - hsum;            // relative exclusive prefix
        int nidx = b * NPB + t;
        float dh = rsqrtf((float)hsum + 1.0f);
        disl[t] = dh;
        if (nidx < NN) {
            rowbe[nidx] = make_int2(wbase + min(exc, MAXB), wbase + min(exc + hsum, MAXB));
            dis[nidx] = dh;
        }
        cur[t] = exc;                               // relative, for sorted[]
    }
    for (int i = t; i < 640; i += 512) Wl[i] = W12g[i];
    __syncthreads();
    // ---- LDS reorder (dst-sorted) then coalesced ssrc writeout ----
    for (int i = t; i < T; i += 512) {
        int p = stage[i];
        int pos = atomicAdd(&cur[p & 255], 1);
        if (pos < MAXB) sorted[pos] = p;
    }
    __syncthreads();
    for (int i = t; i < T; i += 512) ssrc[wbase + i] = sorted[i] >> 8;

    // ---- phase 2: register-direct projection, thread-pair per row ----
    int r = t >> 1, h = t & 1;         // r in 0..255
    int n = b * NPB + r;
    if (n < NN) {
        const float* xr = &x[n * 64 + h * 32];
        float4 xa[8];
        #pragma unroll
        for (int i = 0; i < 8; ++i) xa[i] = *(const float4*)&xr[i * 4];
        float acc[10];
        #pragma unroll
        for (int ch = 0; ch < 10; ++ch) acc[ch] = 0.f;
        #pragma unroll
        for (int i = 0; i < 8; ++i) {
            int k0 = h * 32 + i * 4;
            #pragma unroll
            for (int ch = 0; ch < 10; ++ch) {
                acc[ch] = fmaf(xa[i].x, Wl[(k0 + 0) * 10 + ch], acc[ch]);
                acc[ch] = fmaf(xa[i].y, Wl[(k0 + 1) * 10 + ch], acc[ch]);
                acc[ch] = fmaf(xa[i].z, Wl[(k0 + 2) * 10 + ch], acc[ch]);
                acc[ch] = fmaf(xa[i].w, Wl[(k0 + 3) * 10 + ch], acc[ch]);
            }
        }
        #pragma unroll
        for (int ch = 0; ch < 10; ++ch) acc[ch] += __shfl_xor(acc[ch], 1);
        float dh = disl[r];
        uint4 wv;
        if (h == 0) {   // halves 0-7 = ch0-7
            __half2 p0 = __floats2half2_rn(dh * acc[0], dh * acc[1]);
            __half2 p1 = __floats2half2_rn(dh * acc[2], dh * acc[3]);
            __half2 p2 = __floats2half2_rn(dh * acc[4], dh * acc[5]);
            __half2 p3 = __floats2half2_rn(dh * acc[6], dh * acc[7]);
            wv.x = *(unsigned*)&p0; wv.y = *(unsigned*)&p1;
            wv.z = *(unsigned*)&p2; wv.w = *(unsigned*)&p3;
            ydu[n * 2 + 0] = wv;
        } else {        // halves 8-15 = ch8, ch9, dis, 0, 0,0,0,0
            __half2 p0 = __floats2half2_rn(dh * acc[8], dh * acc[9]);
            __half2 p1 = __floats2half2_rn(dh, 0.f);
            __half2 pz = __floats2half2_rn(0.f, 0.f);
            wv.x = *(unsigned*)&p0; wv.y = *(unsigned*)&p1;
            wv.z = *(unsigned*)&pz; wv.w = *(unsigned*)&pz;
            ydu[n * 2 + 1] = wv;
        }
    }
}

__device__ __forceinline__ float4 cvt4(uint2 v) {
    __half2 h0 = *(__half2*)&v.x, h1 = *(__half2*)&v.y;
    float2 f0 = __half22float2(h0), f1 = __half22float2(h1);
    return make_float4(f0.x, f0.y, f1.x, f1.y);
}

// Pass 1: 4 lanes/node, lane q<3 gathers uint2 (4 halves); 4-deep unroll.
// zd[ch<10] = dis^2*(self+nbrs); zd[10] = dis*(dis-ch sum); zd[11] = 0.
__global__ __launch_bounds__(256) void k_aggA(const uint2* __restrict__ ydu,
                                              const float* __restrict__ dis,
                                              const int2* __restrict__ rowbe,
                                              const int* __restrict__ ssrc,
                                              uint2* __restrict__ zdu) {
    int t = blockIdx.x * blockDim.x + threadIdx.x;
    int n = t >> 2, q = t & 3;
    if (n >= NN) return;
    int2 be = rowbe[n];
    const bool act = (q < 3);
    float4 a0 = make_float4(0.f, 0.f, 0.f, 0.f), a1 = a0, a2 = a0, a3 = a0;
    if (act) a0 = cvt4(ydu[n * 4 + q]);   // self term (dis folded in)
    int j = be.x;
    for (; j + 3 < be.y; j += 4) {
        int s0 = ssrc[j], s1 = ssrc[j + 1], s2 = ssrc[j + 2], s3 = ssrc[j + 3];
        if (act) {
            float4 v0 = cvt4(ydu[s0 * 4 + q]);
            float4 v1 = cvt4(ydu[s1 * 4 + q]);
            float4 v2 = cvt4(ydu[s2 * 4 + q]);
            float4 v3 = cvt4(ydu[s3 * 4 + q]);
            a0.x += v0.x; a0.y += v0.y; a0.z += v0.z; a0.w += v0.w;
            a1.x += v1.x; a1.y += v1.y; a1.z += v1.z; a1.w += v1.w;
            a2.x += v2.x; a2.y += v2.y; a2.z += v2.z; a2.w += v2.w;
            a3.x += v3.x; a3.y += v3.y; a3.z += v3.z; a3.w += v3.w;
        }
    }
    for (; j < be.y; ++j) {
        int s = ssrc[j];
        if (act) {
            float4 v = cvt4(ydu[s * 4 + q]);
            a0.x += v.x; a0.y += v.y; a0.z += v.z; a0.w += v.w;
        }
    }
    if (act) {
        float4 s;
        s.x = (a0.x + a1.x) + (a2.x + a3.x);
        s.y = (a0.y + a1.y) + (a2.y + a3.y);
        s.z = (a0.z + a1.z) + (a2.z + a3.z);
        s.w = (a0.w + a1.w) + (a2.w + a3.w);
        float d = dis[n], d2 = d * d;
        __half2 lo, hi;
        if (q < 2) {
            lo = __floats2half2_rn(d2 * s.x, d2 * s.y);
            hi = __floats2half2_rn(d2 * s.z, d2 * s.w);
        } else {
            lo = __floats2half2_rn(d2 * s.x, d2 * s.y);
            hi = __floats2half2_rn(d * s.z, 0.f);    // n1 = dis * (dis-ch sum)
        }
        uint2 w; w.x = *(unsigned*)&lo; w.y = *(unsigned*)&hi;
        zdu[n * 4 + q] = w;
    }
}

// Pass 2: out[n][c] = dis*(zd self+nbrs)[c] + n1*c1[c] + b2[c].
__global__ __launch_bounds__(256) void k_aggB(const uint2* __restrict__ zdu,
                                              const float* __restrict__ dis,
                                              const int2* __restrict__ rowbe,
                                              const int* __restrict__ ssrc,
                                              const float* __restrict__ c1,
                                              const float* __restrict__ b2,
                                              float* __restrict__ out) {
    int t = blockIdx.x * blockDim.x + threadIdx.x;
    int n = t >> 2, q = t & 3;
    if (n >= NN) return;
    int2 be = rowbe[n];
    const bool act = (q < 3);
    float4 self = make_float4(0.f, 0.f, 0.f, 0.f);
    if (act) self = cvt4(zdu[n * 4 + q]);
    float4 a0 = self, a1 = make_float4(0.f, 0.f, 0.f, 0.f), a2 = a1, a3 = a1;
    int j = be.x;
    for (; j + 3 < be.y; j += 4) {
        int s0 = ssrc[j], s1 = ssrc[j + 1], s2 = ssrc[j + 2], s3 = ssrc[j + 3];
        if (act) {
            float4 v0 = cvt4(zdu[s0 * 4 + q]);
            float4 v1 = cvt4(zdu[s1 * 4 + q]);
            float4 v2 = cvt4(zdu[s2 * 4 + q]);
            float4 v3 = cvt4(zdu[s3 * 4 + q]);
            a0.x += v0.x; a0.y += v0.y; a0.z += v0.z; a0.w += v0.w;
            a1.x += v1.x; a1.y += v1.y; a1.z += v1.z; a1.w += v1.w;
            a2.x += v2.x; a2.y += v2.y; a2.z += v2.z; a2.w += v2.w;
            a3.x += v3.x; a3.y += v3.y; a3.z += v3.z; a3.w += v3.w;
        }
    }
    for (; j < be.y; ++j) {
        int s = ssrc[j];
        if (act) {
            float4 v = cvt4(zdu[s * 4 + q]);
            a0.x += v.x; a0.y += v.y; a0.z += v.z; a0.w += v.w;
        }
    }
    float4 s;
    s.x = (a0.x + a1.x) + (a2.x + a3.x);
    s.y = (a0.y + a1.y) + (a2.y + a3.y);
    s.z = (a0.z + a1.z) + (a2.z + a3.z);
    s.w = (a0.w + a1.w) + (a2.w + a3.w);
    float n1 = __shfl(self.z, 2, 4);   // zd[n][10] from q2's self load
    float d = dis[n];
    if (q == 0) {
        out[n * 10 + 0] = fmaf(d, s.x, fmaf(n1, c1[0], b2[0]));
        out[n * 10 + 1] = fmaf(d, s.y, fmaf(n1, c1[1], b2[1]));
        out[n * 10 + 2] = fmaf(d, s.z, fmaf(n1, c1[2], b2[2]));
        out[n * 10 + 3] = fmaf(d, s.w, fmaf(n1, c1[3], b2[3]));
    } else if (q == 1) {
        out[n * 10 + 4] = fmaf(d, s.x, fmaf(n1, c1[4], b2[4]));
        out[n * 10 + 5] = fmaf(d, s.y, fmaf(n1, c1[5], b2[5]));
        out[n * 10 + 6] = fmaf(d, s.z, fmaf(n1, c1[6], b2[6]));
        out[n * 10 + 7] = fmaf(d, s.w, fmaf(n1, c1[7], b2[7]));
    } else if (q == 2) {
        out[n * 10 + 8] = fmaf(d, s.x, fmaf(n1, c1[8], b2[8]));
        out[n * 10 + 9] = fmaf(d, s.y, fmaf(n1, c1[9], b2[9]));
    }
}

extern "C" void kernel_launch(void* const* d_in, const int* in_sizes, int n_in,
                              void* d_out, int out_size, void* d_ws, size_t ws_size,
                              hipStream_t stream) {
    const float* x  = (const float*)d_in[0];
    const float* W1 = (const float*)d_in[1];
    const float* b1 = (const float*)d_in[2];
    const float* W2 = (const float*)d_in[3];
    const float* b2 = (const float*)d_in[4];
    const int* edge = (const int*)d_in[5];   // [2, NE]: src row then dst row
    const int* src = edge;
    const int* dst = edge + NE;
    float* out = (float*)d_out;

    // Workspace layout (64B-aligned), total ~22.6 MB:
    char* W = (char*)d_ws;
    uint4* ydu    = (uint4*)(W);                   // NN*2 uint4  = 3,200,000 B
    uint4* zdu    = (uint4*)(W + 3200000);         // NN*2 uint4  = 3,200,000 B
    float* dis    = (float*)(W + 6400000);         // NN f        =   400,000 B
    int*   packed = (int*)  (W + 6800000);         // NE i        = 6,400,000 B
    int*   scanT  = (int*)  (W + 13200000);        // NCB*(NB+1)  =   613,088 B
    int*   ssrc   = (int*)  (W + 13813120);        // NB*MAXB i   = 8,007,680 B
    int2*  rowbe  = (int2*) (W + 21820800);        // NN int2     =   800,000 B
    float* W12    = (float*)(W + 22620800);        // 640 f
    float* c1     = (float*)(W + 22623360);        // 10 f

    k_part    <<<NCB + 1, 256, 0, stream>>>(src, dst, W1, W2, b1, packed, scanT, W12, c1);
    k_sortproj<<<NB, 512, 0, stream>>>(packed, scanT, x, W12, ssrc, rowbe, dis, ydu);
    k_aggA    <<<(NN * 4 + 255) / 256, 256, 0, stream>>>((const uint2*)ydu, dis, rowbe, ssrc, (uint2*)zdu);
    k_aggB    <<<(NN * 4 + 255) / 256, 256, 0, stream>>>((const uint2*)zdu, dis, rowbe, ssrc, c1, b2, out);
}